// Round 14
// baseline (425.498 us; speedup 1.0000x reference)
//
#include <hip/hip_runtime.h>
#include <hip/hip_bf16.h>

#define BB 2
#define NN 16384
#define KK 16
#define CC 256
#define NHH 4
#define HDD 64
#define BN (BB*NN)   // 32768
#define HP 260       // hid LDS pitch (ushorts): 520B rows, 8B aligned
#define KVP 512      // KV interleaved row pitch: [0:256)=KA, [256:512)=V

typedef __attribute__((ext_vector_type(8))) short short8;
typedef __attribute__((ext_vector_type(4))) short s4;
typedef __attribute__((ext_vector_type(4))) float f32x4;

__device__ __forceinline__ float bf2f(unsigned short u) {
    union { unsigned u32; float f; } x; x.u32 = ((unsigned)u) << 16; return x.f;
}
__device__ __forceinline__ unsigned short f2bf(float f) {
    union { float f; unsigned u; } x; x.f = f;
    unsigned r = x.u + 0x7FFFu + ((x.u >> 16) & 1u);
    return (unsigned short)(r >> 16);
}
// 16-bf16-byte load from 8B-aligned LDS (two ds_read_b64)
__device__ __forceinline__ short8 ld8_lds(const unsigned short* p) {
    s4 lo = *(const s4*)(p);
    s4 hi = *(const s4*)(p + 4);
    short8 r;
    r[0] = lo[0]; r[1] = lo[1]; r[2] = lo[2]; r[3] = lo[3];
    r[4] = hi[0]; r[5] = hi[1]; r[6] = hi[2]; r[7] = hi[3];
    return r;
}

// ---------------------------------------------------------------------------
// Prep: WqaT = (Wq @ blockdiag(Wa1))^T, WkaT, WpeaT likewise; plain transposes
// WvT, Wp2T, WoT; b_u = bp2 @ blockdiag(Wa1) + tile(ba1); Wp1aT[c][j]=Wp1[j][c]
// (j<4, zero-pad to 8). grid (256, 7), 256 threads.
// ---------------------------------------------------------------------------
__global__ __launch_bounds__(256) void prep_kernel(
    const float* __restrict__ Wq, const float* __restrict__ Wk,
    const float* __restrict__ Wv, const float* __restrict__ Wp2,
    const float* __restrict__ Wo, const float* __restrict__ Wa1,
    const float* __restrict__ bp2, const float* __restrict__ ba1,
    const float* __restrict__ Wp1,
    unsigned short* WqaT, unsigned short* WkaT, unsigned short* WvT,
    unsigned short* WpeaT, unsigned short* Wp2T, unsigned short* WoT,
    float* b_u, unsigned short* Wp1aT)
{
    const int z = blockIdx.y;
    const int t = threadIdx.x;
    if (z < 3) {
        const float* W = (z == 0) ? Wq : (z == 1) ? Wk : Wp2;
        unsigned short* out = (z == 0) ? WqaT : (z == 1) ? WkaT : WpeaT;
        const int k = blockIdx.x;                 // row of W
        __shared__ float wrow[CC];
        __shared__ float a1[HDD * HDD];
        wrow[t] = W[k * CC + t];
        for (int i = t; i < HDD * HDD; i += 256) a1[i] = Wa1[i];
        __syncthreads();
        const int c = t;
        const int h0 = c & ~63;
        const int cl = c & 63;
        float s = 0.f;
        #pragma unroll 8
        for (int j = 0; j < HDD; ++j) s += wrow[h0 + j] * a1[j * HDD + cl];
        out[c * CC + k] = f2bf(s);
    } else if (z < 6) {
        const float* W = (z == 3) ? Wv : (z == 4) ? Wp2 : Wo;
        unsigned short* out = (z == 3) ? WvT : (z == 4) ? Wp2T : WoT;
        const int k = blockIdx.x;
        out[t * CC + k] = f2bf(W[k * CC + t]);
    } else {
        if (blockIdx.x == 0) {
            __shared__ float a1[HDD * HDD];
            for (int i = t; i < HDD * HDD; i += 256) a1[i] = Wa1[i];
            __syncthreads();
            const int c = t;
            const int h0 = c & ~63;
            const int cl = c & 63;
            float s = ba1[cl];
            #pragma unroll 8
            for (int j = 0; j < HDD; ++j) s += bp2[h0 + j] * a1[j * HDD + cl];
            b_u[c] = s;
        } else if (blockIdx.x == 1) {
            const int c = t;
            #pragma unroll
            for (int j = 0; j < 8; ++j)
                Wp1aT[c * 8 + j] = (j < 4) ? f2bf(Wp1[j * CC + c]) : (unsigned short)0;
        }
    }
}

// ---------------------------------------------------------------------------
// 64-row MFMA GEMM: D[m0:m0+64, 0:256] = A[m0:m0+64, :] @ B (BT[col][k]).
// AF32: A is f32 (h) and converted to bf16 inline during LDS staging.
// FINAL=false: z==0 -> QAbf (+b_u fold); z==1 -> KV[...,0:256) (KA);
//              z==2 -> KV[...,256:512) (V).
// FINAL=true : single, f32 out + bias.
// ---------------------------------------------------------------------------
template<bool FINAL, bool AF32>
__global__ __launch_bounds__(256) void gemm64_kernel(
    const void* __restrict__ Asrc,
    const unsigned short* __restrict__ BT0, const unsigned short* __restrict__ BT1,
    const unsigned short* __restrict__ BT2,
    unsigned short* QA, unsigned short* KV,
    float* Dout, const float* __restrict__ bias)
{
    const int m0 = blockIdx.x * 64;
    const unsigned short* BT;
    int z = 0;
    if (!FINAL) {
        z = blockIdx.y;
        BT = (z == 0) ? BT0 : (z == 1) ? BT1 : BT2;
    } else {
        BT = BT0;
    }

    __shared__ __align__(16) unsigned short As[64 * 264];
    const int t = threadIdx.x;
    #pragma unroll
    for (int i = 0; i < 8; ++i) {
        const int flat = i * 2048 + t * 8;
        const int r = flat >> 8, c = flat & 255;
        if (AF32) {
            const float* Af = (const float*)Asrc;
            const float4 v0 = *(const float4*)(Af + (size_t)(m0 + r) * CC + c);
            const float4 v1 = *(const float4*)(Af + (size_t)(m0 + r) * CC + c + 4);
            short8 v;
            v[0] = (short)f2bf(v0.x); v[1] = (short)f2bf(v0.y);
            v[2] = (short)f2bf(v0.z); v[3] = (short)f2bf(v0.w);
            v[4] = (short)f2bf(v1.x); v[5] = (short)f2bf(v1.y);
            v[6] = (short)f2bf(v1.z); v[7] = (short)f2bf(v1.w);
            *(short8*)(&As[r * 264 + c]) = v;
        } else {
            short8 v = *(const short8*)((const unsigned short*)Asrc + (size_t)(m0 + r) * CC + c);
            *(short8*)(&As[r * 264 + c]) = v;
        }
    }
    __syncthreads();

    const int lane = t & 63, w = t >> 6;
    const int lr = lane & 15, lg = lane >> 4;

    f32x4 acc[4][4];
    #pragma unroll
    for (int mi = 0; mi < 4; ++mi)
        #pragma unroll
        for (int ni = 0; ni < 4; ++ni) acc[mi][ni] = (f32x4){0.f, 0.f, 0.f, 0.f};

    #pragma unroll
    for (int kk = 0; kk < 8; ++kk) {
        const int ko = kk * 32 + lg * 8;
        short8 a[4];
        #pragma unroll
        for (int mi = 0; mi < 4; ++mi)
            a[mi] = *(const short8*)(&As[(mi * 16 + lr) * 264 + ko]);
        #pragma unroll
        for (int ni = 0; ni < 4; ++ni) {
            const int col = w * 64 + ni * 16 + lr;
            short8 b = *(const short8*)(BT + (size_t)col * CC + ko);
            #pragma unroll
            for (int mi = 0; mi < 4; ++mi)
                acc[mi][ni] = __builtin_amdgcn_mfma_f32_16x16x32_bf16(a[mi], b, acc[mi][ni], 0, 0, 0);
        }
    }

    #pragma unroll
    for (int mi = 0; mi < 4; ++mi) {
        #pragma unroll
        for (int ni = 0; ni < 4; ++ni) {
            const int col = w * 64 + ni * 16 + lr;
            const float bc = (FINAL || z == 0) ? bias[col] : 0.f;
            #pragma unroll
            for (int reg = 0; reg < 4; ++reg) {
                const int row = m0 + mi * 16 + lg * 4 + reg;
                const float v = acc[mi][ni][reg];
                if (FINAL) {
                    Dout[(size_t)row * CC + col] = v + bias[col];
                } else if (z == 0) {
                    QA[(size_t)row * CC + col] = f2bf(v + bc);
                } else {
                    KV[(size_t)row * KVP + (z == 1 ? 0 : 256) + col] = f2bf(v);
                }
            }
        }
    }
}

// ---------------------------------------------------------------------------
// Fused per-point attention. Block = 4 points x 16 neighbors = 64 rows,
// 256 threads (4 waves; wave w = head w). LDS 39168 B -> 4 blocks/CU.
// r14 = r13 (r7 structure) with the SPILL removed by REGISTER DIET ONLY:
// qab/wa2v/bp1v were loaded at kernel top and held across phases a-b
// (~24 regs held) -> at the 128-reg cap of 4 blocks/CU this forced ~2
// VGPRs/lane of scratch spill (WRITE_SIZE 82MB vs 16.4 legit). Each load
// is now sunk to its use-site; loop structure untouched (r11 showed
// restructuring costs more than spill).
// ---------------------------------------------------------------------------
__global__ __launch_bounds__(256, 4) void fused_attn_kernel(
    const float* __restrict__ P, const int* __restrict__ idx,
    const unsigned short* __restrict__ Wp1aT, const float* __restrict__ bp1,
    const float* __restrict__ Wa2, const float* __restrict__ bp2,
    const unsigned short* __restrict__ QAbf, const unsigned short* __restrict__ KVbf,
    const unsigned short* __restrict__ WpeaT, const unsigned short* __restrict__ Wp2T,
    unsigned short* __restrict__ aggbf)
{
    const int pt0 = blockIdx.x * 4;
    const int b = pt0 >> 14;          // pt0 / NN
    const int n0 = pt0 & (NN - 1);
    const int t = threadIdx.x;
    const int lane = t & 63, w = t >> 6;
    const int lr = lane & 15, lg = lane >> 4;

    __shared__ int nbrL[64];                                   //   256 B
    __shared__ __align__(16) unsigned short geomP[64 * 8];     //  1024 B (bf16, K-pad 8)
    __shared__ __align__(16) unsigned short hidL[64 * HP];     // 33280 B (rows 0..15 reused as hbar)
    __shared__ __align__(16) unsigned short attnA[16 * 72];    //  2304 B (block-diag attn, bf16)
    __shared__ unsigned short vbarL[16 * 72];                  //  2304 B
    // total 39168 B -> 4 blocks/CU

    const short8 zero8 = {0, 0, 0, 0, 0, 0, 0, 0};

    // ---- phase a: indices + geometry (bf16, K-padded) + zero attnA ----
    for (int i = t; i < 576; i += 256) ((unsigned*)attnA)[i] = 0;
    if (t < 64) {
        const int g = t >> 4, k = t & 15;
        const int nb = idx[(size_t)(pt0 + g) * KK + k];
        nbrL[t] = nb;
        const float* Pb = P + (size_t)b * 3 * NN;
        const int nc = n0 + g;
        const float rx = Pb[nb] - Pb[nc];
        const float ry = Pb[NN + nb] - Pb[NN + nc];
        const float rz = Pb[2 * NN + nb] - Pb[2 * NN + nc];
        const float d = sqrtf(rx * rx + ry * ry + rz * rz);
        short8 gp = {(short)f2bf(rx), (short)f2bf(ry), (short)f2bf(rz), (short)f2bf(d),
                     0, 0, 0, 0};
        *(short8*)(&geomP[t * 8]) = gp;
    }
    __syncthreads();

    // ---- phase b: hidden = relu(geom @ Wp1 + bp1) via K=4-padded MFMA ----
    // (bp1 loaded here, at use-site -- not held from kernel top)
    {
        short8 bb[4];
        float bp1v[4];
        #pragma unroll
        for (int ni = 0; ni < 4; ++ni) {
            const int col = w * 64 + ni * 16 + lr;
            bb[ni] = (lg == 0) ? *(const short8*)(Wp1aT + col * 8) : zero8;
            bp1v[ni] = bp1[col];
        }
        #pragma unroll
        for (int mi = 0; mi < 4; ++mi) {
            short8 ag = (lg == 0) ? *(const short8*)(&geomP[(mi * 16 + lr) * 8]) : zero8;
            #pragma unroll
            for (int ni = 0; ni < 4; ++ni) {
                f32x4 ah = (f32x4){bp1v[ni], bp1v[ni], bp1v[ni], bp1v[ni]};
                ah = __builtin_amdgcn_mfma_f32_16x16x32_bf16(ag, bb[ni], ah, 0, 0, 0);
                const int col = w * 64 + ni * 16 + lr;
                #pragma unroll
                for (int reg = 0; reg < 4; ++reg)
                    hidL[(mi * 16 + lg * 4 + reg) * HP + col] = f2bf(fmaxf(ah[reg], 0.f));
            }
        }
    }
    __syncthreads();

    // ---- phase c: acc init = qa(+bu) loaded HERE (not held across a/b);
    //      acc += hidden @ Wpea (MFMA); logits; in-wave softmax ----
    f32x4 acc[4][4];
    #pragma unroll
    for (int mi = 0; mi < 4; ++mi)
        #pragma unroll
        for (int ni = 0; ni < 4; ++ni) {
            const float v = bf2f(QAbf[(size_t)(pt0 + mi) * CC + w * 64 + ni * 16 + lr]);
            acc[mi][ni] = (f32x4){v, v, v, v};
        }

    #pragma unroll
    for (int kk = 0; kk < 8; ++kk) {
        const int ko = kk * 32 + lg * 8;
        short8 a[4];
        #pragma unroll
        for (int mi = 0; mi < 4; ++mi)
            a[mi] = ld8_lds(&hidL[(mi * 16 + lr) * HP + ko]);
        #pragma unroll
        for (int ni = 0; ni < 4; ++ni) {
            const int col = w * 64 + ni * 16 + lr;
            short8 bfr = *(const short8*)(WpeaT + (size_t)col * CC + ko);
            #pragma unroll
            for (int mi = 0; mi < 4; ++mi)
                acc[mi][ni] = __builtin_amdgcn_mfma_f32_16x16x32_bf16(a[mi], bfr, acc[mi][ni], 0, 0, 0);
        }
    }

    // logits + softmax, fully within wave w (= head w); KA loaded per-mi at
    // use (r3/r7 placement); wa2 loaded here, at use-site.
    {
        float wa2v[4];
        #pragma unroll
        for (int ni = 0; ni < 4; ++ni) wa2v[ni] = Wa2[ni * 16 + lr];

        #pragma unroll
        for (int mi = 0; mi < 4; ++mi) {
            unsigned short ka[4][4];
            #pragma unroll
            for (int reg = 0; reg < 4; ++reg) {
                const int r = mi * 16 + lg * 4 + reg;
                const size_t base = ((size_t)b * NN + nbrL[r]) * KVP;   // KA at offset 0
                #pragma unroll
                for (int ni = 0; ni < 4; ++ni)
                    ka[reg][ni] = KVbf[base + w * 64 + ni * 16 + lr];
            }
            float pl[4];
            #pragma unroll
            for (int reg = 0; reg < 4; ++reg) {
                float s = 0.f;
                #pragma unroll
                for (int ni = 0; ni < 4; ++ni) {
                    const float u = acc[mi][ni][reg] - bf2f(ka[reg][ni]);
                    s += fmaxf(u, 0.f) * wa2v[ni];
                }
                s += __shfl_xor(s, 1);
                s += __shfl_xor(s, 2);
                s += __shfl_xor(s, 4);
                s += __shfl_xor(s, 8);
                pl[reg] = s;   // logit for (point mi, k = lg*4+reg)
            }
            float m = fmaxf(fmaxf(pl[0], pl[1]), fmaxf(pl[2], pl[3]));
            m = fmaxf(m, __shfl_xor(m, 16));
            m = fmaxf(m, __shfl_xor(m, 32));
            float e[4], s = 0.f;
            #pragma unroll
            for (int reg = 0; reg < 4; ++reg) { e[reg] = __expf(pl[reg] - m); s += e[reg]; }
            s += __shfl_xor(s, 16);
            s += __shfl_xor(s, 32);
            const float inv = 1.f / s;
            if (lr == 0) {
                #pragma unroll
                for (int reg = 0; reg < 4; ++reg)
                    attnA[(mi * 4 + w) * 72 + mi * 16 + lg * 4 + reg] = f2bf(e[reg] * inv);
            }
        }
    }
    __syncthreads();

    // ---- phase e: issue V loads (rows adjacent to KA rows -> warm L2);
    //      hbar = attnA @ hid via MFMA (into hidL rows 0..15, wave-private
    //      columns); vbar from landed V regs. ----
    const size_t bNN = (size_t)b * NN;
    unsigned short vv[4][16];
    #pragma unroll
    for (int i = 0; i < 4; ++i) {
        const int gh = w * 4 + i;
        const int g = gh >> 2, hh = gh & 3;
        #pragma unroll
        for (int k = 0; k < 16; ++k) {
            const int r = g * 16 + k;
            vv[i][k] = KVbf[(bNN + nbrL[r]) * KVP + 256 + hh * 64 + lane];
        }
    }

    #pragma unroll
    for (int ni = 0; ni < 4; ++ni) {
        const int colAbs = w * 64 + ni * 16 + lr;
        f32x4 ab = (f32x4){0.f, 0.f, 0.f, 0.f};
        #pragma unroll
        for (int kk = 0; kk < 2; ++kk) {
            short8 aa = ld8_lds(&attnA[lr * 72 + kk * 32 + lg * 8]);
            short8 hb;
            #pragma unroll
            for (int j = 0; j < 8; ++j)
                hb[j] = (short)hidL[(kk * 32 + lg * 8 + j) * HP + colAbs];
            ab = __builtin_amdgcn_mfma_f32_16x16x32_bf16(aa, hb, ab, 0, 0, 0);
        }
        #pragma unroll
        for (int reg = 0; reg < 4; ++reg)
            hidL[(lg * 4 + reg) * HP + colAbs] = f2bf(ab[reg]);   // hbar row lg*4+reg
    }

    {
        #pragma unroll
        for (int i = 0; i < 4; ++i) {
            const int gh = w * 4 + i;
            const int g = gh >> 2;
            float s = 0.f;
            #pragma unroll
            for (int k = 0; k < 16; ++k)
                s += bf2f(attnA[gh * 72 + g * 16 + k]) * bf2f(vv[i][k]);
            vbarL[gh * 72 + lane] = f2bf(s);
        }
    }
    __syncthreads();

    // ---- phase f: pe_agg = hbar @ Wp2 (head cols) via MFMA; agg out ----
    f32x4 acc2[4];
    #pragma unroll
    for (int ni = 0; ni < 4; ++ni) acc2[ni] = (f32x4){0.f, 0.f, 0.f, 0.f};
    #pragma unroll
    for (int kk = 0; kk < 8; ++kk) {
        const int ko = kk * 32 + lg * 8;
        short8 a = ld8_lds(&hidL[lr * HP + ko]);   // hbar row lr
        #pragma unroll
        for (int ni = 0; ni < 4; ++ni) {
            const int col = w * 64 + ni * 16 + lr;
            short8 bfr = *(const short8*)(Wp2T + (size_t)col * CC + ko);
            acc2[ni] = __builtin_amdgcn_mfma_f32_16x16x32_bf16(a, bfr, acc2[ni], 0, 0, 0);
        }
    }
    #pragma unroll
    for (int ni = 0; ni < 4; ++ni) {
        const int cl = ni * 16 + lr;
        const int c = w * 64 + cl;
        // output row = lg*4 + reg; rows with hh == w  <=>  reg == w.
        float pv;
        if      (w == 0) pv = acc2[ni][0];
        else if (w == 1) pv = acc2[ni][1];
        else if (w == 2) pv = acc2[ni][2];
        else             pv = acc2[ni][3];
        const float v = pv + bf2f(vbarL[(lg * 4 + w) * 72 + cl]) + bp2[c];
        aggbf[(size_t)(pt0 + lg) * CC + c] = f2bf(v);
    }
}

// ---------------------------------------------------------------------------
extern "C" void kernel_launch(void* const* d_in, const int* in_sizes, int n_in,
                              void* d_out, int out_size, void* d_ws, size_t ws_size,
                              hipStream_t stream)
{
    const float* h   = (const float*)d_in[0];
    const float* P   = (const float*)d_in[1];
    const int*   idx = (const int*)d_in[2];
    const float* Wq  = (const float*)d_in[3];
    const float* Wk  = (const float*)d_in[4];
    const float* Wv  = (const float*)d_in[5];
    const float* Wp1 = (const float*)d_in[6];
    const float* bp1 = (const float*)d_in[7];
    const float* Wp2 = (const float*)d_in[8];
    const float* bp2 = (const float*)d_in[9];
    const float* Wa1 = (const float*)d_in[10];
    const float* ba1 = (const float*)d_in[11];
    const float* Wa2 = (const float*)d_in[12];
    const float* Wo  = (const float*)d_in[14];
    const float* bo  = (const float*)d_in[15];

    char* ws = (char*)d_ws;
    const size_t MB16 = 16777216;   // BN*CC*2 bytes
    unsigned short* WqaT  = (unsigned short*)(ws + 0);
    unsigned short* WkaT  = (unsigned short*)(ws + 131072);
    unsigned short* WvT   = (unsigned short*)(ws + 262144);
    unsigned short* WpeaT = (unsigned short*)(ws + 393216);
    unsigned short* Wp2T  = (unsigned short*)(ws + 524288);
    unsigned short* WoT   = (unsigned short*)(ws + 655360);
    float*          b_u   = (float*)(ws + 786432);
    unsigned short* Wp1aT = (unsigned short*)(ws + 787456);   // 2048 bf16 = 4 KB
    const size_t base = 1 << 20;
    unsigned short* QAbf  = (unsigned short*)(ws + base + 0 * MB16);
    unsigned short* KVbf  = (unsigned short*)(ws + base + 1 * MB16);   // 32 MB (pitch 512)
    unsigned short* aggbf = (unsigned short*)(ws + base + 3 * MB16);
    if (ws_size < base + 4 * MB16) return;   // insufficient scratch -> fail loudly

    prep_kernel<<<dim3(256, 7), 256, 0, stream>>>(Wq, Wk, Wv, Wp2, Wo, Wa1, bp2, ba1, Wp1,
                                                  WqaT, WkaT, WvT, WpeaT, Wp2T, WoT,
                                                  b_u, Wp1aT);
    // A staged directly from f32 h; z==0 folds b_u into QAbf.
    gemm64_kernel<false, true><<<dim3(BN / 64, 3), 256, 0, stream>>>(
        h, WqaT, WkaT, WvT, QAbf, KVbf, nullptr, b_u);
    fused_attn_kernel<<<BN / 4, 256, 0, stream>>>(P, idx, Wp1aT, bp1, Wa2, bp2,
                                                  QAbf, KVbf, WpeaT, Wp2T, aggbf);
    gemm64_kernel<true, false><<<dim3(BN / 64, 1), 256, 0, stream>>>(
        aggbf, WoT, nullptr, nullptr, nullptr, nullptr, (float*)d_out, bo);
}

// Round 15
// 395.128 us; speedup vs baseline: 1.0769x; 1.0769x over previous
//
#include <hip/hip_runtime.h>
#include <hip/hip_bf16.h>

#define BB 2
#define NN 16384
#define KK 16
#define CC 256
#define NHH 4
#define HDD 64
#define BN (BB*NN)   // 32768
#define HP 260       // hid LDS pitch (ushorts): 520B rows, 8B aligned
#define KVP 512      // KV interleaved row pitch: [0:256)=KA, [256:512)=V

typedef __attribute__((ext_vector_type(8))) short short8;
typedef __attribute__((ext_vector_type(4))) short s4;
typedef __attribute__((ext_vector_type(4))) float f32x4;

__device__ __forceinline__ float bf2f(unsigned short u) {
    union { unsigned u32; float f; } x; x.u32 = ((unsigned)u) << 16; return x.f;
}
__device__ __forceinline__ unsigned short f2bf(float f) {
    union { float f; unsigned u; } x; x.f = f;
    unsigned r = x.u + 0x7FFFu + ((x.u >> 16) & 1u);
    return (unsigned short)(r >> 16);
}
// 16-bf16-byte load from 8B-aligned LDS (two ds_read_b64)
__device__ __forceinline__ short8 ld8_lds(const unsigned short* p) {
    s4 lo = *(const s4*)(p);
    s4 hi = *(const s4*)(p + 4);
    short8 r;
    r[0] = lo[0]; r[1] = lo[1]; r[2] = lo[2]; r[3] = lo[3];
    r[4] = hi[0]; r[5] = hi[1]; r[6] = hi[2]; r[7] = hi[3];
    return r;
}

// ---------------------------------------------------------------------------
// Prep: WqaT = (Wq @ blockdiag(Wa1))^T, WkaT, WpeaT likewise; plain transposes
// WvT, Wp2T, WoT; b_u = bp2 @ blockdiag(Wa1) + tile(ba1); Wp1aT[c][j]=Wp1[j][c]
// (j<4, zero-pad to 8). grid (256, 7), 256 threads.
// ---------------------------------------------------------------------------
__global__ __launch_bounds__(256) void prep_kernel(
    const float* __restrict__ Wq, const float* __restrict__ Wk,
    const float* __restrict__ Wv, const float* __restrict__ Wp2,
    const float* __restrict__ Wo, const float* __restrict__ Wa1,
    const float* __restrict__ bp2, const float* __restrict__ ba1,
    const float* __restrict__ Wp1,
    unsigned short* WqaT, unsigned short* WkaT, unsigned short* WvT,
    unsigned short* WpeaT, unsigned short* Wp2T, unsigned short* WoT,
    float* b_u, unsigned short* Wp1aT)
{
    const int z = blockIdx.y;
    const int t = threadIdx.x;
    if (z < 3) {
        const float* W = (z == 0) ? Wq : (z == 1) ? Wk : Wp2;
        unsigned short* out = (z == 0) ? WqaT : (z == 1) ? WkaT : WpeaT;
        const int k = blockIdx.x;                 // row of W
        __shared__ float wrow[CC];
        __shared__ float a1[HDD * HDD];
        wrow[t] = W[k * CC + t];
        for (int i = t; i < HDD * HDD; i += 256) a1[i] = Wa1[i];
        __syncthreads();
        const int c = t;
        const int h0 = c & ~63;
        const int cl = c & 63;
        float s = 0.f;
        #pragma unroll 8
        for (int j = 0; j < HDD; ++j) s += wrow[h0 + j] * a1[j * HDD + cl];
        out[c * CC + k] = f2bf(s);
    } else if (z < 6) {
        const float* W = (z == 3) ? Wv : (z == 4) ? Wp2 : Wo;
        unsigned short* out = (z == 3) ? WvT : (z == 4) ? Wp2T : WoT;
        const int k = blockIdx.x;
        out[t * CC + k] = f2bf(W[k * CC + t]);
    } else {
        if (blockIdx.x == 0) {
            __shared__ float a1[HDD * HDD];
            for (int i = t; i < HDD * HDD; i += 256) a1[i] = Wa1[i];
            __syncthreads();
            const int c = t;
            const int h0 = c & ~63;
            const int cl = c & 63;
            float s = ba1[cl];
            #pragma unroll 8
            for (int j = 0; j < HDD; ++j) s += bp2[h0 + j] * a1[j * HDD + cl];
            b_u[c] = s;
        } else if (blockIdx.x == 1) {
            const int c = t;
            #pragma unroll
            for (int j = 0; j < 8; ++j)
                Wp1aT[c * 8 + j] = (j < 4) ? f2bf(Wp1[j * CC + c]) : (unsigned short)0;
        }
    }
}

// ---------------------------------------------------------------------------
// 64-row MFMA GEMM: D[m0:m0+64, 0:256] = A[m0:m0+64, :] @ B (BT[col][k]).
// AF32: A is f32 (h) and converted to bf16 inline during LDS staging
//       (identical rounding to the old h2bf pass -- that kernel is removed).
// FINAL=false: 3 weight/dest via blockIdx.y. z==0 -> QAbf (+b_u bias fold,
//   stride CC); z==1 -> KV[...,0:256) (KA); z==2 -> KV[...,256:512) (V).
//   KA and V rows for the same point are ADJACENT -> warm pages when the
//   fused kernel gathers V after KA for the same neighbors.
// FINAL=true : single, f32 out + bias.
// ---------------------------------------------------------------------------
template<bool FINAL, bool AF32>
__global__ __launch_bounds__(256) void gemm64_kernel(
    const void* __restrict__ Asrc,
    const unsigned short* __restrict__ BT0, const unsigned short* __restrict__ BT1,
    const unsigned short* __restrict__ BT2,
    unsigned short* QA, unsigned short* KV,
    float* Dout, const float* __restrict__ bias)
{
    const int m0 = blockIdx.x * 64;
    const unsigned short* BT;
    int z = 0;
    if (!FINAL) {
        z = blockIdx.y;
        BT = (z == 0) ? BT0 : (z == 1) ? BT1 : BT2;
    } else {
        BT = BT0;
    }

    __shared__ __align__(16) unsigned short As[64 * 264];
    const int t = threadIdx.x;
    #pragma unroll
    for (int i = 0; i < 8; ++i) {
        const int flat = i * 2048 + t * 8;
        const int r = flat >> 8, c = flat & 255;
        if (AF32) {
            const float* Af = (const float*)Asrc;
            const float4 v0 = *(const float4*)(Af + (size_t)(m0 + r) * CC + c);
            const float4 v1 = *(const float4*)(Af + (size_t)(m0 + r) * CC + c + 4);
            short8 v;
            v[0] = (short)f2bf(v0.x); v[1] = (short)f2bf(v0.y);
            v[2] = (short)f2bf(v0.z); v[3] = (short)f2bf(v0.w);
            v[4] = (short)f2bf(v1.x); v[5] = (short)f2bf(v1.y);
            v[6] = (short)f2bf(v1.z); v[7] = (short)f2bf(v1.w);
            *(short8*)(&As[r * 264 + c]) = v;
        } else {
            short8 v = *(const short8*)((const unsigned short*)Asrc + (size_t)(m0 + r) * CC + c);
            *(short8*)(&As[r * 264 + c]) = v;
        }
    }
    __syncthreads();

    const int lane = t & 63, w = t >> 6;
    const int lr = lane & 15, lg = lane >> 4;

    f32x4 acc[4][4];
    #pragma unroll
    for (int mi = 0; mi < 4; ++mi)
        #pragma unroll
        for (int ni = 0; ni < 4; ++ni) acc[mi][ni] = (f32x4){0.f, 0.f, 0.f, 0.f};

    #pragma unroll
    for (int kk = 0; kk < 8; ++kk) {
        const int ko = kk * 32 + lg * 8;
        short8 a[4];
        #pragma unroll
        for (int mi = 0; mi < 4; ++mi)
            a[mi] = *(const short8*)(&As[(mi * 16 + lr) * 264 + ko]);
        #pragma unroll
        for (int ni = 0; ni < 4; ++ni) {
            const int col = w * 64 + ni * 16 + lr;
            short8 b = *(const short8*)(BT + (size_t)col * CC + ko);
            #pragma unroll
            for (int mi = 0; mi < 4; ++mi)
                acc[mi][ni] = __builtin_amdgcn_mfma_f32_16x16x32_bf16(a[mi], b, acc[mi][ni], 0, 0, 0);
        }
    }

    #pragma unroll
    for (int mi = 0; mi < 4; ++mi) {
        #pragma unroll
        for (int ni = 0; ni < 4; ++ni) {
            const int col = w * 64 + ni * 16 + lr;
            const float bc = (FINAL || z == 0) ? bias[col] : 0.f;
            #pragma unroll
            for (int reg = 0; reg < 4; ++reg) {
                const int row = m0 + mi * 16 + lg * 4 + reg;
                const float v = acc[mi][ni][reg];
                if (FINAL) {
                    Dout[(size_t)row * CC + col] = v + bias[col];
                } else if (z == 0) {
                    QA[(size_t)row * CC + col] = f2bf(v + bc);
                } else {
                    // KV interleave: KA at offset 0, V at offset 256
                    KV[(size_t)row * KVP + (z == 1 ? 0 : 256) + col] = f2bf(v);
                }
            }
        }
    }
}

// ---------------------------------------------------------------------------
// Fused per-point attention. Block = 4 points x 16 neighbors = 64 rows,
// 256 threads (4 waves; wave w = head w). LDS 39168 B -> 4 blocks/CU.
// This is the r7/r13 structure -- the empirical optimum of 14 rounds
// (fused 348us). Ten structural attacks (occupancy, conflicts, prefetch x3,
// barrier count/type, wave autonomy, spill removal x2) all regressed or were
// neutral. Binding constraint: dependent random-gather latency at the
// register-capped 16-wave/CU occupancy (~6 outstanding lines/CU vs ~500cy
// L2/L3 latency) -- structural, not a pipe roofline.
// Known/accepted: ~66MB/dispatch spill at the 128-reg cap; r11/r14 showed
// both restructuring and register-diet fixes cost more than the spill.
// ---------------------------------------------------------------------------
__global__ __launch_bounds__(256, 4) void fused_attn_kernel(
    const float* __restrict__ P, const int* __restrict__ idx,
    const unsigned short* __restrict__ Wp1aT, const float* __restrict__ bp1,
    const float* __restrict__ Wa2, const float* __restrict__ bp2,
    const unsigned short* __restrict__ QAbf, const unsigned short* __restrict__ KVbf,
    const unsigned short* __restrict__ WpeaT, const unsigned short* __restrict__ Wp2T,
    unsigned short* __restrict__ aggbf)
{
    const int pt0 = blockIdx.x * 4;
    const int b = pt0 >> 14;          // pt0 / NN
    const int n0 = pt0 & (NN - 1);
    const int t = threadIdx.x;
    const int lane = t & 63, w = t >> 6;
    const int lr = lane & 15, lg = lane >> 4;

    __shared__ int nbrL[64];                                   //   256 B
    __shared__ __align__(16) unsigned short geomP[64 * 8];     //  1024 B (bf16, K-pad 8)
    __shared__ __align__(16) unsigned short hidL[64 * HP];     // 33280 B (rows 0..15 reused as hbar)
    __shared__ __align__(16) unsigned short attnA[16 * 72];    //  2304 B (block-diag attn, bf16)
    __shared__ unsigned short vbarL[16 * 72];                  //  2304 B
    // total 39168 B -> 4 blocks/CU

    const short8 zero8 = {0, 0, 0, 0, 0, 0, 0, 0};

    // ---- early register loads (drained at first barrier; cheap) ----
    float qab[4][4];      // QA[pt0+mi][w*64+ni*16+lr]  (b_u already folded in)
    float wa2v[4], bp1v[4];
    #pragma unroll
    for (int ni = 0; ni < 4; ++ni) {
        const int c = w * 64 + ni * 16 + lr;
        wa2v[ni] = Wa2[ni * 16 + lr];
        bp1v[ni] = bp1[c];
        #pragma unroll
        for (int mi = 0; mi < 4; ++mi)
            qab[mi][ni] = bf2f(QAbf[(size_t)(pt0 + mi) * CC + c]);
    }

    // ---- phase a: indices + geometry (bf16, K-padded) + zero attnA ----
    for (int i = t; i < 576; i += 256) ((unsigned*)attnA)[i] = 0;
    if (t < 64) {
        const int g = t >> 4, k = t & 15;
        const int nb = idx[(size_t)(pt0 + g) * KK + k];
        nbrL[t] = nb;
        const float* Pb = P + (size_t)b * 3 * NN;
        const int nc = n0 + g;
        const float rx = Pb[nb] - Pb[nc];
        const float ry = Pb[NN + nb] - Pb[NN + nc];
        const float rz = Pb[2 * NN + nb] - Pb[2 * NN + nc];
        const float d = sqrtf(rx * rx + ry * ry + rz * rz);
        short8 gp = {(short)f2bf(rx), (short)f2bf(ry), (short)f2bf(rz), (short)f2bf(d),
                     0, 0, 0, 0};
        *(short8*)(&geomP[t * 8]) = gp;
    }
    __syncthreads();

    // ---- phase b: hidden = relu(geom @ Wp1 + bp1) via K=4-padded MFMA ----
    {
        short8 bb[4];
        #pragma unroll
        for (int ni = 0; ni < 4; ++ni) {
            const int col = w * 64 + ni * 16 + lr;
            bb[ni] = (lg == 0) ? *(const short8*)(Wp1aT + col * 8) : zero8;
        }
        #pragma unroll
        for (int mi = 0; mi < 4; ++mi) {
            short8 ag = (lg == 0) ? *(const short8*)(&geomP[(mi * 16 + lr) * 8]) : zero8;
            #pragma unroll
            for (int ni = 0; ni < 4; ++ni) {
                f32x4 ah = (f32x4){bp1v[ni], bp1v[ni], bp1v[ni], bp1v[ni]};
                ah = __builtin_amdgcn_mfma_f32_16x16x32_bf16(ag, bb[ni], ah, 0, 0, 0);
                const int col = w * 64 + ni * 16 + lr;
                #pragma unroll
                for (int reg = 0; reg < 4; ++reg)
                    hidL[(mi * 16 + lg * 4 + reg) * HP + col] = f2bf(fmaxf(ah[reg], 0.f));
            }
        }
    }
    __syncthreads();

    // ---- phase c: acc = qa(+bu); acc += hidden @ Wpea (MFMA); logits; softmax ----
    f32x4 acc[4][4];
    #pragma unroll
    for (int mi = 0; mi < 4; ++mi)
        #pragma unroll
        for (int ni = 0; ni < 4; ++ni) {
            const float v = qab[mi][ni];
            acc[mi][ni] = (f32x4){v, v, v, v};
        }

    #pragma unroll
    for (int kk = 0; kk < 8; ++kk) {
        const int ko = kk * 32 + lg * 8;
        short8 a[4];
        #pragma unroll
        for (int mi = 0; mi < 4; ++mi)
            a[mi] = ld8_lds(&hidL[(mi * 16 + lr) * HP + ko]);
        #pragma unroll
        for (int ni = 0; ni < 4; ++ni) {
            const int col = w * 64 + ni * 16 + lr;
            short8 bfr = *(const short8*)(WpeaT + (size_t)col * CC + ko);
            #pragma unroll
            for (int mi = 0; mi < 4; ++mi)
                acc[mi][ni] = __builtin_amdgcn_mfma_f32_16x16x32_bf16(a[mi], bfr, acc[mi][ni], 0, 0, 0);
        }
    }

    // logits + softmax, fully within wave w (= head w); KA loaded per-mi at use
    // (r3/r7 placement -- interleaves gather latency with shuffle/VALU work).
    #pragma unroll
    for (int mi = 0; mi < 4; ++mi) {
        unsigned short ka[4][4];
        #pragma unroll
        for (int reg = 0; reg < 4; ++reg) {
            const int r = mi * 16 + lg * 4 + reg;
            const size_t base = ((size_t)b * NN + nbrL[r]) * KVP;   // KA at offset 0
            #pragma unroll
            for (int ni = 0; ni < 4; ++ni)
                ka[reg][ni] = KVbf[base + w * 64 + ni * 16 + lr];
        }
        float pl[4];
        #pragma unroll
        for (int reg = 0; reg < 4; ++reg) {
            float s = 0.f;
            #pragma unroll
            for (int ni = 0; ni < 4; ++ni) {
                const float u = acc[mi][ni][reg] - bf2f(ka[reg][ni]);
                s += fmaxf(u, 0.f) * wa2v[ni];
            }
            s += __shfl_xor(s, 1);
            s += __shfl_xor(s, 2);
            s += __shfl_xor(s, 4);
            s += __shfl_xor(s, 8);
            pl[reg] = s;   // logit for (point mi, k = lg*4+reg); same across lr
        }
        float m = fmaxf(fmaxf(pl[0], pl[1]), fmaxf(pl[2], pl[3]));
        m = fmaxf(m, __shfl_xor(m, 16));
        m = fmaxf(m, __shfl_xor(m, 32));
        float e[4], s = 0.f;
        #pragma unroll
        for (int reg = 0; reg < 4; ++reg) { e[reg] = __expf(pl[reg] - m); s += e[reg]; }
        s += __shfl_xor(s, 16);
        s += __shfl_xor(s, 32);
        const float inv = 1.f / s;
        if (lr == 0) {
            #pragma unroll
            for (int reg = 0; reg < 4; ++reg)
                attnA[(mi * 4 + w) * 72 + mi * 16 + lg * 4 + reg] = f2bf(e[reg] * inv);
        }
    }
    __syncthreads();

    // ---- phase e: issue V loads (rows adjacent to the KA rows just read ->
    //      warm pages/L2 sets); hbar = attnA @ hid via MFMA (into hidL rows
    //      0..15, wave-private columns); vbar from landed V regs. ----
    const size_t bNN = (size_t)b * NN;
    unsigned short vv[4][16];
    #pragma unroll
    for (int i = 0; i < 4; ++i) {
        const int gh = w * 4 + i;
        const int g = gh >> 2, hh = gh & 3;
        #pragma unroll
        for (int k = 0; k < 16; ++k) {
            const int r = g * 16 + k;
            vv[i][k] = KVbf[(bNN + nbrL[r]) * KVP + 256 + hh * 64 + lane];
        }
    }

    #pragma unroll
    for (int ni = 0; ni < 4; ++ni) {
        const int colAbs = w * 64 + ni * 16 + lr;
        f32x4 ab = (f32x4){0.f, 0.f, 0.f, 0.f};
        #pragma unroll
        for (int kk = 0; kk < 2; ++kk) {
            short8 aa = ld8_lds(&attnA[lr * 72 + kk * 32 + lg * 8]);
            short8 hb;
            #pragma unroll
            for (int j = 0; j < 8; ++j)
                hb[j] = (short)hidL[(kk * 32 + lg * 8 + j) * HP + colAbs];
            ab = __builtin_amdgcn_mfma_f32_16x16x32_bf16(aa, hb, ab, 0, 0, 0);
        }
        #pragma unroll
        for (int reg = 0; reg < 4; ++reg)
            hidL[(lg * 4 + reg) * HP + colAbs] = f2bf(ab[reg]);   // hbar row lg*4+reg
    }

    {
        #pragma unroll
        for (int i = 0; i < 4; ++i) {
            const int gh = w * 4 + i;
            const int g = gh >> 2;
            float s = 0.f;
            #pragma unroll
            for (int k = 0; k < 16; ++k)
                s += bf2f(attnA[gh * 72 + g * 16 + k]) * bf2f(vv[i][k]);
            vbarL[gh * 72 + lane] = f2bf(s);
        }
    }
    __syncthreads();

    // ---- phase f: pe_agg = hbar @ Wp2 (head cols) via MFMA; agg out ----
    f32x4 acc2[4];
    #pragma unroll
    for (int ni = 0; ni < 4; ++ni) acc2[ni] = (f32x4){0.f, 0.f, 0.f, 0.f};
    #pragma unroll
    for (int kk = 0; kk < 8; ++kk) {
        const int ko = kk * 32 + lg * 8;
        short8 a = ld8_lds(&hidL[lr * HP + ko]);   // hbar row lr
        #pragma unroll
        for (int ni = 0; ni < 4; ++ni) {
            const int col = w * 64 + ni * 16 + lr;
            short8 bfr = *(const short8*)(Wp2T + (size_t)col * CC + ko);
            acc2[ni] = __builtin_amdgcn_mfma_f32_16x16x32_bf16(a, bfr, acc2[ni], 0, 0, 0);
        }
    }
    #pragma unroll
    for (int ni = 0; ni < 4; ++ni) {
        const int cl = ni * 16 + lr;
        const int c = w * 64 + cl;
        // output row = lg*4 + reg; rows with hh == w  <=>  reg == w.
        float pv;
        if      (w == 0) pv = acc2[ni][0];
        else if (w == 1) pv = acc2[ni][1];
        else if (w == 2) pv = acc2[ni][2];
        else             pv = acc2[ni][3];
        const float v = pv + bf2f(vbarL[(lg * 4 + w) * 72 + cl]) + bp2[c];
        aggbf[(size_t)(pt0 + lg) * CC + c] = f2bf(v);
    }
}

// ---------------------------------------------------------------------------
extern "C" void kernel_launch(void* const* d_in, const int* in_sizes, int n_in,
                              void* d_out, int out_size, void* d_ws, size_t ws_size,
                              hipStream_t stream)
{
    const float* h   = (const float*)d_in[0];
    const float* P   = (const float*)d_in[1];
    const int*   idx = (const int*)d_in[2];
    const float* Wq  = (const float*)d_in[3];
    const float* Wk  = (const float*)d_in[4];
    const float* Wv  = (const float*)d_in[5];
    const float* Wp1 = (const float*)d_in[6];
    const float* bp1 = (const float*)d_in[7];
    const float* Wp2 = (const float*)d_in[8];
    const float* bp2 = (const float*)d_in[9];
    const float* Wa1 = (const float*)d_in[10];
    const float* ba1 = (const float*)d_in[11];
    const float* Wa2 = (const float*)d_in[12];
    const float* Wo  = (const float*)d_in[14];
    const float* bo  = (const float*)d_in[15];

    char* ws = (char*)d_ws;
    const size_t MB16 = 16777216;   // BN*CC*2 bytes
    unsigned short* WqaT  = (unsigned short*)(ws + 0);
    unsigned short* WkaT  = (unsigned short*)(ws + 131072);
    unsigned short* WvT   = (unsigned short*)(ws + 262144);
    unsigned short* WpeaT = (unsigned short*)(ws + 393216);
    unsigned short* Wp2T  = (unsigned short*)(ws + 524288);
    unsigned short* WoT   = (unsigned short*)(ws + 655360);
    float*          b_u   = (float*)(ws + 786432);
    unsigned short* Wp1aT = (unsigned short*)(ws + 787456);   // 2048 bf16 = 4 KB
    const size_t base = 1 << 20;
    unsigned short* QAbf  = (unsigned short*)(ws + base + 0 * MB16);
    unsigned short* KVbf  = (unsigned short*)(ws + base + 1 * MB16);   // 32 MB (pitch 512)
    unsigned short* aggbf = (unsigned short*)(ws + base + 3 * MB16);
    if (ws_size < base + 4 * MB16) return;   // insufficient scratch -> fail loudly

    prep_kernel<<<dim3(256, 7), 256, 0, stream>>>(Wq, Wk, Wv, Wp2, Wo, Wa1, bp2, ba1, Wp1,
                                                  WqaT, WkaT, WvT, WpeaT, Wp2T, WoT,
                                                  b_u, Wp1aT);
    // A staged directly from f32 h (h2bf kernel removed); z==0 folds b_u.
    gemm64_kernel<false, true><<<dim3(BN / 64, 3), 256, 0, stream>>>(
        h, WqaT, WkaT, WvT, QAbf, KVbf, nullptr, b_u);
    fused_attn_kernel<<<BN / 4, 256, 0, stream>>>(P, idx, Wp1aT, bp1, Wa2, bp2,
                                                  QAbf, KVbf, WpeaT, Wp2T, aggbf);
    gemm64_kernel<true, false><<<dim3(BN / 64, 1), 256, 0, stream>>>(
        aggbf, WoT, nullptr, nullptr, nullptr, nullptr, (float*)d_out, bo);
}